// Round 3
// baseline (285.841 us; speedup 1.0000x reference)
//
#include <hip/hip_runtime.h>
#include <stdint.h>

#define D_DIM 2048
#define OUT_DIM 2048
#define NTOK 16384
#define SCALING 1.0f
#define NT_TILES 34   // 32 K-tiles of x@W^T + 2 LoRA-extension tiles

typedef unsigned short u16;
typedef __attribute__((ext_vector_type(8))) short s16x8;
typedef __attribute__((ext_vector_type(4))) float f32x4;

// ws layout (bytes)
#define WZ_OFF  0u           // W bf16 swizzled [2048 o][2048 d]
#define AZ_OFF  8388608u     // experts_A^T bf16 swizzled [128 er][2048 d]
#define BZ_OFF  8912896u     // experts_B^T bf16 swizzled [2048 o][128 er]
#define CZ_OFF  9437184u     // c bf16 swizzled [16384 t][128 er]
#define W8_OFF  13631488u    // router weights f32 [16384][8]
#define XB_OFF  14155776u    // x bf16 swizzled [16384][2048]
#define WS_BIG   81264640u

__device__ inline u16 f2bf(float f) {
  union { float f; uint32_t u; } v; v.f = f;
  uint32_t u = v.u;
  u += 0x7FFFu + ((u >> 16) & 1u);   // round-to-nearest-even
  return (u16)(u >> 16);
}

// ---------------- prep kernels: cast + pre-swizzle into global ----------------
// swizzle: within each 64-elem chunk of a row, elem_col ^= (row&7)<<3
__global__ __launch_bounds__(256) void k_prep_w(const float* __restrict__ W,
                                                u16* __restrict__ Wz) {
  int idx = blockIdx.x * 256 + threadIdx.x;
  int o  = idx >> 9;
  int k0 = (idx & 511) * 4;
  const float4 v = *(const float4*)&W[(size_t)o * D_DIM + k0];
  int s = (o & 7) << 3;
  int dst = (k0 & ~63) | ((k0 & 63) ^ s);
  uint32_t p0 = (uint32_t)f2bf(v.x) | ((uint32_t)f2bf(v.y) << 16);
  uint32_t p1 = (uint32_t)f2bf(v.z) | ((uint32_t)f2bf(v.w) << 16);
  *(uint2*)&Wz[(size_t)o * D_DIM + dst] = make_uint2(p0, p1);
}

__global__ __launch_bounds__(256) void k_prep_a(const float* __restrict__ A,
                                                u16* __restrict__ Az) {
  int idx = blockIdx.x * 256 + threadIdx.x;      // 8*2048*16
  float v = A[idx];
  int r = idx & 15;
  int d = (idx >> 4) & 2047;
  int e = idx >> 15;
  int er = e * 16 + r;
  int s = (er & 7) << 3;
  int dst = (d & ~63) | ((d & 63) ^ s);
  Az[(size_t)er * D_DIM + dst] = f2bf(v);
}

__global__ __launch_bounds__(256) void k_prep_b(const float* __restrict__ Bf,
                                                u16* __restrict__ Bz) {
  int idx = blockIdx.x * 256 + threadIdx.x;      // 128*2048
  float v = Bf[idx];
  int er = idx >> 11;
  int o  = idx & 2047;
  int s = (o & 7) << 3;
  int dst = (er & 64) | ((er & 63) ^ s);
  Bz[(size_t)o * 128 + dst] = f2bf(v);
}

// ------- fused router + x precast: f32 logits, top-2, softmax; xb swizzled ----
__global__ __launch_bounds__(256) void k_router_xb(const float* __restrict__ x,
                                                   const float* __restrict__ rw,
                                                   float* __restrict__ w8,
                                                   u16* __restrict__ xb) {
  int lane = threadIdx.x & 63, wid = threadIdx.x >> 6;
  int t = blockIdx.x * 4 + wid;
  const float* xr = x + (size_t)t * D_DIM;
  float4 xv[8];
#pragma unroll
  for (int j = 0; j < 8; ++j) xv[j] = *(const float4*)&xr[j * 256 + lane * 4];
  int s = (t & 7) << 3;
#pragma unroll
  for (int j = 0; j < 8; ++j) {
    int c4 = j * 256 + lane * 4;
    int dst = (c4 & ~63) | ((c4 & 63) ^ s);
    uint32_t p0 = (uint32_t)f2bf(xv[j].x) | ((uint32_t)f2bf(xv[j].y) << 16);
    uint32_t p1 = (uint32_t)f2bf(xv[j].z) | ((uint32_t)f2bf(xv[j].w) << 16);
    *(uint2*)&xb[(size_t)t * D_DIM + dst] = make_uint2(p0, p1);
  }
  float lg[8];
#pragma unroll
  for (int e = 0; e < 8; ++e) {
    float a = 0.f;
#pragma unroll
    for (int j = 0; j < 8; ++j) {
      float4 rv = *(const float4*)&rw[e * D_DIM + j * 256 + lane * 4];
      a = fmaf(xv[j].x, rv.x, a); a = fmaf(xv[j].y, rv.y, a);
      a = fmaf(xv[j].z, rv.z, a); a = fmaf(xv[j].w, rv.w, a);
    }
#pragma unroll
    for (int off = 32; off; off >>= 1) a += __shfl_xor(a, off, 64);
    lg[e] = a;
  }
  int i0 = 0;
#pragma unroll
  for (int e = 1; e < 8; ++e) if (lg[e] > lg[i0]) i0 = e;
  int i1 = (i0 == 0) ? 1 : 0;
#pragma unroll
  for (int e = 0; e < 8; ++e) if (e != i0 && lg[e] > lg[i1]) i1 = e;
  float e1 = expf(lg[i1] - lg[i0]);
  float inv = 1.f / (1.f + e1);
  float w0 = inv * SCALING, w1 = e1 * inv * SCALING;
  if (lane < 8)
    w8[(size_t)t * 8 + lane] = (lane == i0) ? w0 : (lane == i1) ? w1 : 0.f;
}

// ---------------- lora-down: c = (xb @ A_all) * w8 -> Cz (M-tile 64) ----------
__global__ __launch_bounds__(256) void k_lora64(const u16* __restrict__ xb,
                                                const u16* __restrict__ Az,
                                                const float* __restrict__ w8,
                                                u16* __restrict__ Cz) {
  __shared__ u16 Alds[64 * 64];
  __shared__ u16 Blds[128 * 64];
  __shared__ float w8s[64 * 8];
  int tid = threadIdx.x, lane = tid & 63, wid = tid >> 6;
  int t0 = blockIdx.x * 64;
  w8s[tid] = w8[(size_t)t0 * 8 + tid];
  w8s[256 + tid] = w8[(size_t)t0 * 8 + 256 + tid];
  f32x4 acc[8];
#pragma unroll
  for (int n = 0; n < 8; ++n) acc[n] = (f32x4){0.f, 0.f, 0.f, 0.f};
  const int ce = (lane >> 4) * 8;
  for (int kc = 0; kc < 32; ++kc) {
    __syncthreads();
#pragma unroll
    for (int i = 0; i < 2; ++i) {
      const u16* g = xb + (size_t)(t0 + i * 32 + (tid >> 3)) * D_DIM + kc * 64 + (tid & 7) * 8;
      __builtin_amdgcn_global_load_lds(
          (const __attribute__((address_space(1))) void*)g,
          (__attribute__((address_space(3))) void*)(Alds + i * 2048 + tid * 8), 16, 0, 0);
    }
#pragma unroll
    for (int i = 0; i < 4; ++i) {
      const u16* g = Az + (size_t)(i * 32 + (tid >> 3)) * D_DIM + kc * 64 + (tid & 7) * 8;
      __builtin_amdgcn_global_load_lds(
          (const __attribute__((address_space(1))) void*)g,
          (__attribute__((address_space(3))) void*)(Blds + i * 2048 + tid * 8), 16, 0, 0);
    }
    __syncthreads();
#pragma unroll
    for (int kk = 0; kk < 2; ++kk) {
      int ar = wid * 16 + (lane & 15);
      s16x8 af = *(const s16x8*)&Alds[ar * 64 + ((ce + kk * 32) ^ ((ar & 7) << 3))];
#pragma unroll
      for (int nf = 0; nf < 8; ++nf) {
        int br = nf * 16 + (lane & 15);
        s16x8 bf = *(const s16x8*)&Blds[br * 64 + ((ce + kk * 32) ^ ((br & 7) << 3))];
        acc[nf] = __builtin_amdgcn_mfma_f32_16x16x32_bf16(af, bf, acc[nf], 0, 0, 0);
      }
    }
  }
#pragma unroll
  for (int q = 0; q < 4; ++q) {
    int rloc = wid * 16 + (lane >> 4) * 4 + q;
#pragma unroll
    for (int nf = 0; nf < 8; ++nf) {
      int er = nf * 16 + (lane & 15);
      float v = acc[nf][q] * w8s[rloc * 8 + (er >> 4)];
      int dst = (er & 64) | ((er & 63) ^ ((rloc & 7) << 3));
      Cz[(size_t)(t0 + rloc) * 128 + dst] = f2bf(v);
    }
  }
}

// ---------------- 256^2 8-phase main GEMM -------------------------------------
__device__ inline void stg(int kt, int h, int t0, int o0,
                           const u16* __restrict__ xb, const u16* __restrict__ Wz,
                           const u16* __restrict__ Cz, const u16* __restrict__ Bz,
                           u16* AshP, u16* BshP, int tid) {
  if (kt >= NT_TILES) return;
  int p = kt & 1;
  const u16* src; int ld; size_t r0; int c0; u16* dst;
  if (h < 2) {
    if (kt < 32) { src = xb; ld = D_DIM; c0 = kt * 64; }
    else         { src = Cz; ld = 128;   c0 = (kt - 32) * 64; }
    r0 = (size_t)t0 + h * 128;
    dst = AshP + p * 16384 + h * 8192;
  } else {
    if (kt < 32) { src = Wz; ld = D_DIM; c0 = kt * 64; }
    else         { src = Bz; ld = 128;   c0 = (kt - 32) * 64; }
    r0 = (size_t)o0 + (h - 2) * 128;
    dst = BshP + p * 16384 + (h - 2) * 8192;
  }
#pragma unroll
  for (int i = 0; i < 2; ++i) {
    const u16* g = src + (r0 + i * 64 + (tid >> 3)) * (size_t)ld + c0 + (tid & 7) * 8;
    __builtin_amdgcn_global_load_lds(
        (const __attribute__((address_space(1))) void*)g,
        (__attribute__((address_space(3))) void*)(dst + i * 4096 + tid * 8), 16, 0, 0);
  }
}

__device__ inline void read_af(const u16* buf, int rbase, int ce, s16x8 a[4][2]) {
#pragma unroll
  for (int i = 0; i < 4; ++i)
#pragma unroll
    for (int kk = 0; kk < 2; ++kk) {
      int r = rbase + i * 16;
      a[i][kk] = *(const s16x8*)&buf[r * 64 + ((ce + kk * 32) ^ ((r & 7) << 3))];
    }
}

template <int MFH, int NFH>
__device__ inline void mfma_quad(f32x4 acc[8][4], const s16x8 a[4][2],
                                 const s16x8 b[4][2]) {
#pragma unroll
  for (int i = 0; i < 4; ++i)
#pragma unroll
    for (int j = 0; j < 2; ++j)
#pragma unroll
      for (int kk = 0; kk < 2; ++kk)
        acc[MFH * 4 + i][NFH * 2 + j] = __builtin_amdgcn_mfma_f32_16x16x32_bf16(
            a[i][kk], b[NFH * 2 + j][kk], acc[MFH * 4 + i][NFH * 2 + j], 0, 0, 0);
}

__global__ __launch_bounds__(512, 2) void k_main8(const u16* __restrict__ xb,
                                                  const u16* __restrict__ Wz,
                                                  const u16* __restrict__ Cz,
                                                  const u16* __restrict__ Bz,
                                                  float* __restrict__ out) {
  __shared__ u16 Ash[2][16384];
  __shared__ u16 Bsh[2][16384];
  const int tid = threadIdx.x, lane = tid & 63;
  const int wid = tid >> 6, wm = wid >> 2, wn = wid & 3;
  int bid = blockIdx.x;                     // 512 blocks, 512 % 8 == 0
  int swz = (bid & 7) * 64 + (bid >> 3);    // XCD-aware, bijective
  int mt = swz >> 3, nt = swz & 7;
  int t0 = mt * 256, o0 = nt * 256;
  const int ce = (lane >> 4) * 8;
  const int arb = wm * 128 + (lane & 15);
  const int brb = wn * 64 + (lane & 15);
  u16* A0 = &Ash[0][0];
  u16* B0 = &Bsh[0][0];

  f32x4 acc[8][4];
#pragma unroll
  for (int m = 0; m < 8; ++m)
#pragma unroll
    for (int n = 0; n < 4; ++n) acc[m][n] = (f32x4){0.f, 0.f, 0.f, 0.f};
  s16x8 a[4][2], b[4][2];

  // prologue: tile0 all 4 halves + tile1 A-half0
  stg(0, 0, t0, o0, xb, Wz, Cz, Bz, A0, B0, tid);
  stg(0, 1, t0, o0, xb, Wz, Cz, Bz, A0, B0, tid);
  stg(0, 2, t0, o0, xb, Wz, Cz, Bz, A0, B0, tid);
  stg(0, 3, t0, o0, xb, Wz, Cz, Bz, A0, B0, tid);
  stg(1, 0, t0, o0, xb, Wz, Cz, Bz, A0, B0, tid);
  asm volatile("s_waitcnt vmcnt(2)" ::: "memory");
  __builtin_amdgcn_s_barrier();

  for (int kt = 0; kt < NT_TILES; ++kt) {
    const int p = kt & 1;
    // ---- q0: read A mf0-3 + all B; stage (kt+1, A-half1)
    read_af(&Ash[p][0], arb, ce, a);
    read_af(&Bsh[p][0], brb, ce, b);
    stg(kt + 1, 1, t0, o0, xb, Wz, Cz, Bz, A0, B0, tid);
    __builtin_amdgcn_s_barrier();
    asm volatile("s_waitcnt lgkmcnt(0)" ::: "memory");
    __builtin_amdgcn_sched_barrier(0);
    __builtin_amdgcn_s_setprio(1);
    mfma_quad<0, 0>(acc, a, b);
    __builtin_amdgcn_s_setprio(0);
    __builtin_amdgcn_s_barrier();
    // ---- q1: stage (kt+1, B-half0)
    stg(kt + 1, 2, t0, o0, xb, Wz, Cz, Bz, A0, B0, tid);
    __builtin_amdgcn_s_barrier();
    __builtin_amdgcn_s_setprio(1);
    mfma_quad<0, 1>(acc, a, b);
    __builtin_amdgcn_s_setprio(0);
    __builtin_amdgcn_s_barrier();
    // ---- q2: read A mf4-7; stage (kt+1, B-half1)
    read_af(&Ash[p][0], arb + 64, ce, a);
    stg(kt + 1, 3, t0, o0, xb, Wz, Cz, Bz, A0, B0, tid);
    __builtin_amdgcn_s_barrier();
    asm volatile("s_waitcnt lgkmcnt(0)" ::: "memory");
    __builtin_amdgcn_sched_barrier(0);
    __builtin_amdgcn_s_setprio(1);
    mfma_quad<1, 0>(acc, a, b);
    __builtin_amdgcn_s_setprio(0);
    __builtin_amdgcn_s_barrier();
    // ---- q3: stage (kt+2, A-half0) into buf[p] (fully read by q2); counted vmcnt
    stg(kt + 2, 0, t0, o0, xb, Wz, Cz, Bz, A0, B0, tid);
    asm volatile("s_waitcnt vmcnt(2)" ::: "memory");
    __builtin_amdgcn_s_barrier();
    __builtin_amdgcn_s_setprio(1);
    mfma_quad<1, 1>(acc, a, b);
    __builtin_amdgcn_s_setprio(0);
    __builtin_amdgcn_s_barrier();
  }

#pragma unroll
  for (int mf = 0; mf < 8; ++mf)
#pragma unroll
    for (int q = 0; q < 4; ++q) {
      int row = t0 + wm * 128 + mf * 16 + (lane >> 4) * 4 + q;
#pragma unroll
      for (int nf = 0; nf < 4; ++nf) {
        int col = o0 + wn * 64 + nf * 16 + (lane & 15);
        out[(size_t)row * OUT_DIM + col] = acc[mf][nf][q];
      }
    }
}

extern "C" void kernel_launch(void* const* d_in, const int* in_sizes, int n_in,
                              void* d_out, int out_size, void* d_ws, size_t ws_size,
                              hipStream_t stream) {
  const float* x  = (const float*)d_in[0];
  const float* W  = (const float*)d_in[1];
  const float* rw = (const float*)d_in[2];
  const float* eA = (const float*)d_in[3];
  const float* eB = (const float*)d_in[4];
  float* out = (float*)d_out;
  char* ws = (char*)d_ws;
  if (ws_size < WS_BIG) return;

  u16*   Wz = (u16*)(ws + WZ_OFF);
  u16*   Az = (u16*)(ws + AZ_OFF);
  u16*   Bz = (u16*)(ws + BZ_OFF);
  u16*   Cz = (u16*)(ws + CZ_OFF);
  float* w8 = (float*)(ws + W8_OFF);
  u16*   xb = (u16*)(ws + XB_OFF);

  k_prep_w<<<4096, 256, 0, stream>>>(W, Wz);
  k_prep_a<<<1024, 256, 0, stream>>>(eA, Az);
  k_prep_b<<<1024, 256, 0, stream>>>(eB, Bz);
  k_router_xb<<<4096, 256, 0, stream>>>(x, rw, w8, xb);
  k_lora64<<<256, 256, 0, stream>>>(xb, Az, w8, Cz);
  k_main8<<<512, 512, 0, stream>>>(xb, Wz, Cz, Bz, out);
}

// Round 4
// 267.070 us; speedup vs baseline: 1.0703x; 1.0703x over previous
//
#include <hip/hip_runtime.h>
#include <stdint.h>

#define D_DIM 2048
#define OUT_DIM 2048
#define NTOK 16384
#define SCALING 1.0f
#define NT_TILES 34   // 32 K-tiles of x@W^T + 2 LoRA-extension tiles

typedef unsigned short u16;
typedef __attribute__((ext_vector_type(8))) short s16x8;
typedef __attribute__((ext_vector_type(4))) float f32x4;

// ws layout (bytes)
#define WZ_OFF  0u           // W bf16 swizzled [2048 o][2048 d]
#define AZ_OFF  8388608u     // experts_A^T bf16 swizzled [128 er][2048 d]
#define BZ_OFF  8912896u     // experts_B^T bf16 swizzled [2048 o][128 er]
#define CZ_OFF  9437184u     // c bf16 swizzled [16384 t][128 er]
#define W8_OFF  13631488u    // router weights f32 [16384][8]
#define XB_OFF  14155776u    // x bf16 swizzled [16384][2048]
#define WS_BIG   81264640u

__device__ inline u16 f2bf(float f) {
  union { float f; uint32_t u; } v; v.f = f;
  uint32_t u = v.u;
  u += 0x7FFFu + ((u >> 16) & 1u);   // round-to-nearest-even
  return (u16)(u >> 16);
}

// -------- merged prep: cast + pre-swizzle W / experts_A^T / experts_B^T -------
// swizzle: within each 64-elem chunk of a row, elem_col ^= (row&7)<<3
__global__ __launch_bounds__(256) void k_prep(const float* __restrict__ W,
                                              const float* __restrict__ A,
                                              const float* __restrict__ Bf,
                                              u16* __restrict__ Wz,
                                              u16* __restrict__ Az,
                                              u16* __restrict__ Bz) {
  int bid = blockIdx.x;
  if (bid < 4096) {
    int idx = bid * 256 + threadIdx.x;
    int o  = idx >> 9;
    int k0 = (idx & 511) * 4;
    const float4 v = *(const float4*)&W[(size_t)o * D_DIM + k0];
    int s = (o & 7) << 3;
    int dst = (k0 & ~63) | ((k0 & 63) ^ s);
    uint32_t p0 = (uint32_t)f2bf(v.x) | ((uint32_t)f2bf(v.y) << 16);
    uint32_t p1 = (uint32_t)f2bf(v.z) | ((uint32_t)f2bf(v.w) << 16);
    *(uint2*)&Wz[(size_t)o * D_DIM + dst] = make_uint2(p0, p1);
  } else if (bid < 5120) {
    int idx = (bid - 4096) * 256 + threadIdx.x;    // 8*2048*16
    float v = A[idx];
    int r = idx & 15;
    int d = (idx >> 4) & 2047;
    int e = idx >> 15;
    int er = e * 16 + r;
    int s = (er & 7) << 3;
    int dst = (d & ~63) | ((d & 63) ^ s);
    Az[(size_t)er * D_DIM + dst] = f2bf(v);
  } else {
    int idx = (bid - 5120) * 256 + threadIdx.x;    // 128*2048
    float v = Bf[idx];
    int er = idx >> 11;
    int o  = idx & 2047;
    int s = (o & 7) << 3;
    int dst = (er & 64) | ((er & 63) ^ s);
    Bz[(size_t)o * 128 + dst] = f2bf(v);
  }
}

// ------- fused router + x precast: f32 logits, top-2, softmax; xb swizzled ----
__global__ __launch_bounds__(256) void k_router_xb(const float* __restrict__ x,
                                                   const float* __restrict__ rw,
                                                   float* __restrict__ w8,
                                                   u16* __restrict__ xb) {
  int lane = threadIdx.x & 63, wid = threadIdx.x >> 6;
  int t = blockIdx.x * 4 + wid;
  const float* xr = x + (size_t)t * D_DIM;
  float4 xv[8];
#pragma unroll
  for (int j = 0; j < 8; ++j) xv[j] = *(const float4*)&xr[j * 256 + lane * 4];
  int s = (t & 7) << 3;
#pragma unroll
  for (int j = 0; j < 8; ++j) {
    int c4 = j * 256 + lane * 4;
    int dst = (c4 & ~63) | ((c4 & 63) ^ s);
    uint32_t p0 = (uint32_t)f2bf(xv[j].x) | ((uint32_t)f2bf(xv[j].y) << 16);
    uint32_t p1 = (uint32_t)f2bf(xv[j].z) | ((uint32_t)f2bf(xv[j].w) << 16);
    *(uint2*)&xb[(size_t)t * D_DIM + dst] = make_uint2(p0, p1);
  }
  float lg[8];
#pragma unroll
  for (int e = 0; e < 8; ++e) {
    float a = 0.f;
#pragma unroll
    for (int j = 0; j < 8; ++j) {
      float4 rv = *(const float4*)&rw[e * D_DIM + j * 256 + lane * 4];
      a = fmaf(xv[j].x, rv.x, a); a = fmaf(xv[j].y, rv.y, a);
      a = fmaf(xv[j].z, rv.z, a); a = fmaf(xv[j].w, rv.w, a);
    }
#pragma unroll
    for (int off = 32; off; off >>= 1) a += __shfl_xor(a, off, 64);
    lg[e] = a;
  }
  int i0 = 0;
#pragma unroll
  for (int e = 1; e < 8; ++e) if (lg[e] > lg[i0]) i0 = e;
  int i1 = (i0 == 0) ? 1 : 0;
#pragma unroll
  for (int e = 0; e < 8; ++e) if (e != i0 && lg[e] > lg[i1]) i1 = e;
  float e1 = expf(lg[i1] - lg[i0]);
  float inv = 1.f / (1.f + e1);
  float w0 = inv * SCALING, w1 = e1 * inv * SCALING;
  if (lane < 8)
    w8[(size_t)t * 8 + lane] = (lane == i0) ? w0 : (lane == i1) ? w1 : 0.f;
}

// ---------------- lora-down: c = (xb @ A_all) * w8 -> Cz (M-tile 64) ----------
__global__ __launch_bounds__(256) void k_lora64(const u16* __restrict__ xb,
                                                const u16* __restrict__ Az,
                                                const float* __restrict__ w8,
                                                u16* __restrict__ Cz) {
  __shared__ u16 Alds[64 * 64];
  __shared__ u16 Blds[128 * 64];
  __shared__ float w8s[64 * 8];
  int tid = threadIdx.x, lane = tid & 63, wid = tid >> 6;
  int t0 = blockIdx.x * 64;
  w8s[tid] = w8[(size_t)t0 * 8 + tid];
  w8s[256 + tid] = w8[(size_t)t0 * 8 + 256 + tid];
  f32x4 acc[8];
#pragma unroll
  for (int n = 0; n < 8; ++n) acc[n] = (f32x4){0.f, 0.f, 0.f, 0.f};
  const int ce = (lane >> 4) * 8;
  for (int kc = 0; kc < 32; ++kc) {
    __syncthreads();
#pragma unroll
    for (int i = 0; i < 2; ++i) {
      const u16* g = xb + (size_t)(t0 + i * 32 + (tid >> 3)) * D_DIM + kc * 64 + (tid & 7) * 8;
      __builtin_amdgcn_global_load_lds(
          (const __attribute__((address_space(1))) void*)g,
          (__attribute__((address_space(3))) void*)(Alds + i * 2048 + tid * 8), 16, 0, 0);
    }
#pragma unroll
    for (int i = 0; i < 4; ++i) {
      const u16* g = Az + (size_t)(i * 32 + (tid >> 3)) * D_DIM + kc * 64 + (tid & 7) * 8;
      __builtin_amdgcn_global_load_lds(
          (const __attribute__((address_space(1))) void*)g,
          (__attribute__((address_space(3))) void*)(Blds + i * 2048 + tid * 8), 16, 0, 0);
    }
    __syncthreads();
#pragma unroll
    for (int kk = 0; kk < 2; ++kk) {
      int ar = wid * 16 + (lane & 15);
      s16x8 af = *(const s16x8*)&Alds[ar * 64 + ((ce + kk * 32) ^ ((ar & 7) << 3))];
#pragma unroll
      for (int nf = 0; nf < 8; ++nf) {
        int br = nf * 16 + (lane & 15);
        s16x8 bf = *(const s16x8*)&Blds[br * 64 + ((ce + kk * 32) ^ ((br & 7) << 3))];
        acc[nf] = __builtin_amdgcn_mfma_f32_16x16x32_bf16(af, bf, acc[nf], 0, 0, 0);
      }
    }
  }
#pragma unroll
  for (int q = 0; q < 4; ++q) {
    int rloc = wid * 16 + (lane >> 4) * 4 + q;
#pragma unroll
    for (int nf = 0; nf < 8; ++nf) {
      int er = nf * 16 + (lane & 15);
      float v = acc[nf][q] * w8s[rloc * 8 + (er >> 4)];
      int dst = (er & 64) | ((er & 63) ^ ((rloc & 7) << 3));
      Cz[(size_t)(t0 + rloc) * 128 + dst] = f2bf(v);
    }
  }
}

// ---------------- 256^2 8-phase main GEMM (deep-pipelined) --------------------
__device__ inline void stg(int kt, int h, int t0, int o0,
                           const u16* __restrict__ xb, const u16* __restrict__ Wz,
                           const u16* __restrict__ Cz, const u16* __restrict__ Bz,
                           u16* AshP, u16* BshP, int tid) {
  int p = kt & 1;
  const u16* src; int ld; size_t r0; int c0; u16* dst;
  if (h < 2) {
    if (kt < 32) { src = xb; ld = D_DIM; c0 = kt * 64; }
    else         { src = Cz; ld = 128;   c0 = (kt - 32) * 64; }
    r0 = (size_t)t0 + h * 128;
    dst = AshP + p * 16384 + h * 8192;
  } else {
    if (kt < 32) { src = Wz; ld = D_DIM; c0 = kt * 64; }
    else         { src = Bz; ld = 128;   c0 = (kt - 32) * 64; }
    r0 = (size_t)o0 + (h - 2) * 128;
    dst = BshP + p * 16384 + (h - 2) * 8192;
  }
#pragma unroll
  for (int i = 0; i < 2; ++i) {
    const u16* g = src + (r0 + i * 64 + (tid >> 3)) * (size_t)ld + c0 + (tid & 7) * 8;
    __builtin_amdgcn_global_load_lds(
        (const __attribute__((address_space(1))) void*)g,
        (__attribute__((address_space(3))) void*)(dst + i * 4096 + tid * 8), 16, 0, 0);
  }
}

__device__ inline void read_af(const u16* buf, int rbase, int ce, s16x8 a[4][2]) {
#pragma unroll
  for (int i = 0; i < 4; ++i)
#pragma unroll
    for (int kk = 0; kk < 2; ++kk) {
      int r = rbase + i * 16;
      a[i][kk] = *(const s16x8*)&buf[r * 64 + ((ce + kk * 32) ^ ((r & 7) << 3))];
    }
}

__device__ inline void read_b2(const u16* buf, int rbase, int ce, s16x8 b[4][2], int h) {
#pragma unroll
  for (int i = 0; i < 2; ++i)
#pragma unroll
    for (int kk = 0; kk < 2; ++kk) {
      int r = rbase + (h * 2 + i) * 16;
      b[h * 2 + i][kk] = *(const s16x8*)&buf[r * 64 + ((ce + kk * 32) ^ ((r & 7) << 3))];
    }
}

template <int MFH, int NFH>
__device__ inline void mfma_quad(f32x4 acc[8][4], const s16x8 a[4][2],
                                 const s16x8 b[4][2]) {
#pragma unroll
  for (int i = 0; i < 4; ++i)
#pragma unroll
    for (int j = 0; j < 2; ++j)
#pragma unroll
      for (int kk = 0; kk < 2; ++kk)
        acc[MFH * 4 + i][NFH * 2 + j] = __builtin_amdgcn_mfma_f32_16x16x32_bf16(
            a[i][kk], b[NFH * 2 + j][kk], acc[MFH * 4 + i][NFH * 2 + j], 0, 0, 0);
}

__global__ __launch_bounds__(512, 2) void k_main8(const u16* __restrict__ xb,
                                                  const u16* __restrict__ Wz,
                                                  const u16* __restrict__ Cz,
                                                  const u16* __restrict__ Bz,
                                                  float* __restrict__ out) {
  __shared__ u16 Ash[2][16384];
  __shared__ u16 Bsh[2][16384];
  const int tid = threadIdx.x, lane = tid & 63;
  const int wid = tid >> 6, wm = wid >> 2, wn = wid & 3;
  int bid = blockIdx.x;                     // 512 blocks, 512 % 8 == 0
  int swz = (bid & 7) * 64 + (bid >> 3);    // XCD-aware, bijective
  int mt = swz >> 3, nt = swz & 7;
  int t0 = mt * 256, o0 = nt * 256;
  const int ce = (lane >> 4) * 8;
  const int arb = wm * 128 + (lane & 15);
  const int brb = wn * 64 + (lane & 15);
  u16* A0 = &Ash[0][0];
  u16* B0 = &Bsh[0][0];

  f32x4 acc[8][4];
#pragma unroll
  for (int m = 0; m < 8; ++m)
#pragma unroll
    for (int n = 0; n < 4; ++n) acc[m][n] = (f32x4){0.f, 0.f, 0.f, 0.f};
  s16x8 a[4][2], b[4][2];

  // prologue: tile0 (4 halves) + tile1 (4 halves); wait for tile0 only
  stg(0, 0, t0, o0, xb, Wz, Cz, Bz, A0, B0, tid);
  stg(0, 1, t0, o0, xb, Wz, Cz, Bz, A0, B0, tid);
  stg(0, 2, t0, o0, xb, Wz, Cz, Bz, A0, B0, tid);
  stg(0, 3, t0, o0, xb, Wz, Cz, Bz, A0, B0, tid);
  stg(1, 0, t0, o0, xb, Wz, Cz, Bz, A0, B0, tid);
  stg(1, 1, t0, o0, xb, Wz, Cz, Bz, A0, B0, tid);
  stg(1, 2, t0, o0, xb, Wz, Cz, Bz, A0, B0, tid);
  stg(1, 3, t0, o0, xb, Wz, Cz, Bz, A0, B0, tid);
  asm volatile("s_waitcnt vmcnt(8)" ::: "memory");
  __builtin_amdgcn_s_barrier();

  for (int kt = 0; kt < NT_TILES; ++kt) {
    const int p = kt & 1;
    const u16* Abuf = &Ash[p][0];
    const u16* Bbuf = &Bsh[p][0];
    const int ktc = (kt + 2 < NT_TILES) ? kt + 2 : NT_TILES - 1;  // clamped prefetch
    // ---- P1: read a-lo + b-lo; MFMA q(0,0)
    read_af(Abuf, arb, ce, a);
    read_b2(Bbuf, brb, ce, b, 0);
    __builtin_amdgcn_s_barrier();
    asm volatile("s_waitcnt lgkmcnt(0)" ::: "memory");
    __builtin_amdgcn_sched_barrier(0);
    __builtin_amdgcn_s_setprio(1);
    mfma_quad<0, 0>(acc, a, b);
    __builtin_amdgcn_s_setprio(0);
    __builtin_amdgcn_s_barrier();
    // ---- P2: read b-hi; MFMA q(0,1)
    read_b2(Bbuf, brb, ce, b, 1);
    __builtin_amdgcn_s_barrier();
    asm volatile("s_waitcnt lgkmcnt(0)" ::: "memory");
    __builtin_amdgcn_sched_barrier(0);
    __builtin_amdgcn_s_setprio(1);
    mfma_quad<0, 1>(acc, a, b);
    __builtin_amdgcn_s_setprio(0);
    __builtin_amdgcn_s_barrier();
    // ---- P3: read a-hi; stage (kt+2).B0,B1 into buf[p] (freed after P2); q(1,0)
    read_af(Abuf, arb + 64, ce, a);
    stg(ktc, 2, t0, o0, xb, Wz, Cz, Bz, A0, B0, tid);
    stg(ktc, 3, t0, o0, xb, Wz, Cz, Bz, A0, B0, tid);
    __builtin_amdgcn_s_barrier();
    asm volatile("s_waitcnt lgkmcnt(0)" ::: "memory");
    __builtin_amdgcn_sched_barrier(0);
    __builtin_amdgcn_s_setprio(1);
    mfma_quad<1, 0>(acc, a, b);
    __builtin_amdgcn_s_setprio(0);
    __builtin_amdgcn_s_barrier();
    // ---- P4: stage (kt+2).A0,A1 (freed after P3); counted vmcnt(8); q(1,1)
    stg(ktc, 0, t0, o0, xb, Wz, Cz, Bz, A0, B0, tid);
    stg(ktc, 1, t0, o0, xb, Wz, Cz, Bz, A0, B0, tid);
    asm volatile("s_waitcnt vmcnt(8)" ::: "memory");
    __builtin_amdgcn_s_barrier();
    __builtin_amdgcn_s_setprio(1);
    mfma_quad<1, 1>(acc, a, b);
    __builtin_amdgcn_s_setprio(0);
    __builtin_amdgcn_s_barrier();
  }

#pragma unroll
  for (int mf = 0; mf < 8; ++mf)
#pragma unroll
    for (int q = 0; q < 4; ++q) {
      int row = t0 + wm * 128 + mf * 16 + (lane >> 4) * 4 + q;
#pragma unroll
      for (int nf = 0; nf < 4; ++nf) {
        int col = o0 + wn * 64 + nf * 16 + (lane & 15);
        out[(size_t)row * OUT_DIM + col] = acc[mf][nf][q];
      }
    }
}

extern "C" void kernel_launch(void* const* d_in, const int* in_sizes, int n_in,
                              void* d_out, int out_size, void* d_ws, size_t ws_size,
                              hipStream_t stream) {
  const float* x  = (const float*)d_in[0];
  const float* W  = (const float*)d_in[1];
  const float* rw = (const float*)d_in[2];
  const float* eA = (const float*)d_in[3];
  const float* eB = (const float*)d_in[4];
  float* out = (float*)d_out;
  char* ws = (char*)d_ws;
  if (ws_size < WS_BIG) return;

  u16*   Wz = (u16*)(ws + WZ_OFF);
  u16*   Az = (u16*)(ws + AZ_OFF);
  u16*   Bz = (u16*)(ws + BZ_OFF);
  u16*   Cz = (u16*)(ws + CZ_OFF);
  float* w8 = (float*)(ws + W8_OFF);
  u16*   xb = (u16*)(ws + XB_OFF);

  k_prep<<<6144, 256, 0, stream>>>(W, eA, eB, Wz, Az, Bz);
  k_router_xb<<<4096, 256, 0, stream>>>(x, rw, w8, xb);
  k_lora64<<<256, 256, 0, stream>>>(xb, Az, w8, Cz);
  k_main8<<<512, 512, 0, stream>>>(xb, Wz, Cz, Bz, out);
}

// Round 5
// 250.799 us; speedup vs baseline: 1.1397x; 1.0649x over previous
//
#include <hip/hip_runtime.h>
#include <stdint.h>

#define D_DIM 2048
#define OUT_DIM 2048
#define NTOK 16384
#define SCALING 1.0f
#define NT_TILES 34   // 32 K-tiles of x@W^T + 2 LoRA-extension tiles

typedef unsigned short u16;
typedef __attribute__((ext_vector_type(8))) short s16x8;
typedef __attribute__((ext_vector_type(4))) float f32x4;

// ws layout (bytes)
#define WZ_OFF  0u           // W bf16 swizzled [2048 o][2048 d]
#define AZ_OFF  8388608u     // experts_A^T bf16 swizzled [128 er][2048 d]
#define BZ_OFF  8912896u     // experts_B^T bf16 swizzled [2048 o][128 er]
#define CZ_OFF  9437184u     // c bf16 swizzled [16384 t][128 er]
#define W8_OFF  13631488u    // router weights f32 [16384][8]
#define XB_OFF  14155776u    // x bf16 swizzled [16384][2048]
#define WS_BIG   81264640u

__device__ inline u16 f2bf(float f) {
  union { float f; uint32_t u; } v; v.f = f;
  uint32_t u = v.u;
  u += 0x7FFFu + ((u >> 16) & 1u);   // round-to-nearest-even
  return (u16)(u >> 16);
}

// ---- merged prep + router: cast/swizzle W,A^T,B^T; router logits + xb cast ---
__global__ __launch_bounds__(256) void k_prep_router(
    const float* __restrict__ W, const float* __restrict__ A,
    const float* __restrict__ Bf, const float* __restrict__ x,
    const float* __restrict__ rw,
    u16* __restrict__ Wz, u16* __restrict__ Az, u16* __restrict__ Bz,
    float* __restrict__ w8, u16* __restrict__ xb) {
  int bid = blockIdx.x;
  if (bid < 4096) {                      // W: 2048x2048 f32 -> bf16 swizzled
    int idx = bid * 256 + threadIdx.x;
    int o  = idx >> 9;
    int k0 = (idx & 511) * 4;
    const float4 v = *(const float4*)&W[(size_t)o * D_DIM + k0];
    int s = (o & 7) << 3;
    int dst = (k0 & ~63) | ((k0 & 63) ^ s);
    uint32_t p0 = (uint32_t)f2bf(v.x) | ((uint32_t)f2bf(v.y) << 16);
    uint32_t p1 = (uint32_t)f2bf(v.z) | ((uint32_t)f2bf(v.w) << 16);
    *(uint2*)&Wz[(size_t)o * D_DIM + dst] = make_uint2(p0, p1);
    return;
  }
  if (bid < 5120) {                      // experts_A -> A^T swizzled
    int idx = (bid - 4096) * 256 + threadIdx.x;
    float v = A[idx];
    int r = idx & 15;
    int d = (idx >> 4) & 2047;
    int e = idx >> 15;
    int er = e * 16 + r;
    int s = (er & 7) << 3;
    int dst = (d & ~63) | ((d & 63) ^ s);
    Az[(size_t)er * D_DIM + dst] = f2bf(v);
    return;
  }
  if (bid < 6144) {                      // experts_B -> B^T swizzled
    int idx = (bid - 5120) * 256 + threadIdx.x;
    float v = Bf[idx];
    int er = idx >> 11;
    int o  = idx & 2047;
    int s = (o & 7) << 3;
    int dst = (er & 64) | ((er & 63) ^ s);
    Bz[(size_t)o * 128 + dst] = f2bf(v);
    return;
  }
  // router + xb precast: one wave per token
  int lane = threadIdx.x & 63, wid = threadIdx.x >> 6;
  int t = (bid - 6144) * 4 + wid;
  const float* xr = x + (size_t)t * D_DIM;
  float4 xv[8];
#pragma unroll
  for (int j = 0; j < 8; ++j) xv[j] = *(const float4*)&xr[j * 256 + lane * 4];
  int s = (t & 7) << 3;
#pragma unroll
  for (int j = 0; j < 8; ++j) {
    int c4 = j * 256 + lane * 4;
    int dst = (c4 & ~63) | ((c4 & 63) ^ s);
    uint32_t p0 = (uint32_t)f2bf(xv[j].x) | ((uint32_t)f2bf(xv[j].y) << 16);
    uint32_t p1 = (uint32_t)f2bf(xv[j].z) | ((uint32_t)f2bf(xv[j].w) << 16);
    *(uint2*)&xb[(size_t)t * D_DIM + dst] = make_uint2(p0, p1);
  }
  float lg[8];
#pragma unroll
  for (int e = 0; e < 8; ++e) {
    float a = 0.f;
#pragma unroll
    for (int j = 0; j < 8; ++j) {
      float4 rv = *(const float4*)&rw[e * D_DIM + j * 256 + lane * 4];
      a = fmaf(xv[j].x, rv.x, a); a = fmaf(xv[j].y, rv.y, a);
      a = fmaf(xv[j].z, rv.z, a); a = fmaf(xv[j].w, rv.w, a);
    }
#pragma unroll
    for (int off = 32; off; off >>= 1) a += __shfl_xor(a, off, 64);
    lg[e] = a;
  }
  int i0 = 0;
#pragma unroll
  for (int e = 1; e < 8; ++e) if (lg[e] > lg[i0]) i0 = e;
  int i1 = (i0 == 0) ? 1 : 0;
#pragma unroll
  for (int e = 0; e < 8; ++e) if (e != i0 && lg[e] > lg[i1]) i1 = e;
  float e1 = expf(lg[i1] - lg[i0]);
  float inv = 1.f / (1.f + e1);
  float w0 = inv * SCALING, w1 = e1 * inv * SCALING;
  if (lane < 8)
    w8[(size_t)t * 8 + lane] = (lane == i0) ? w0 : (lane == i1) ? w1 : 0.f;
}

// ---------------- lora-down: c = (xb @ A_all) * w8 -> Cz (M-tile 64) ----------
// minimum 2-phase pipeline: stage(next) -> ds_read(cur) -> MFMA -> vmcnt(0)+bar
__global__ __launch_bounds__(256) void k_lora64(const u16* __restrict__ xb,
                                                const u16* __restrict__ Az,
                                                const float* __restrict__ w8,
                                                u16* __restrict__ Cz) {
  __shared__ u16 Alds[2][64 * 64];
  __shared__ u16 Blds[2][128 * 64];
  __shared__ float w8s[64 * 8];
  int tid = threadIdx.x, lane = tid & 63, wid = tid >> 6;
  int t0 = blockIdx.x * 64;
  w8s[tid] = w8[(size_t)t0 * 8 + tid];
  w8s[256 + tid] = w8[(size_t)t0 * 8 + 256 + tid];
  f32x4 acc[8];
#pragma unroll
  for (int n = 0; n < 8; ++n) acc[n] = (f32x4){0.f, 0.f, 0.f, 0.f};
  const int ce = (lane >> 4) * 8;

  auto stage = [&](int kc, int buf) {
    if (kc > 31) kc = 31;
#pragma unroll
    for (int i = 0; i < 2; ++i) {
      const u16* g = xb + (size_t)(t0 + i * 32 + (tid >> 3)) * D_DIM + kc * 64 + (tid & 7) * 8;
      __builtin_amdgcn_global_load_lds(
          (const __attribute__((address_space(1))) void*)g,
          (__attribute__((address_space(3))) void*)(&Alds[buf][0] + i * 2048 + tid * 8), 16, 0, 0);
    }
#pragma unroll
    for (int i = 0; i < 4; ++i) {
      const u16* g = Az + (size_t)(i * 32 + (tid >> 3)) * D_DIM + kc * 64 + (tid & 7) * 8;
      __builtin_amdgcn_global_load_lds(
          (const __attribute__((address_space(1))) void*)g,
          (__attribute__((address_space(3))) void*)(&Blds[buf][0] + i * 2048 + tid * 8), 16, 0, 0);
    }
  };

  stage(0, 0);
  asm volatile("s_waitcnt vmcnt(0)" ::: "memory");
  __builtin_amdgcn_s_barrier();
  for (int kc = 0; kc < 32; ++kc) {
    int cur = kc & 1;
    stage(kc + 1, cur ^ 1);
#pragma unroll
    for (int kk = 0; kk < 2; ++kk) {
      int ar = wid * 16 + (lane & 15);
      s16x8 af = *(const s16x8*)&Alds[cur][ar * 64 + ((ce + kk * 32) ^ ((ar & 7) << 3))];
#pragma unroll
      for (int nf = 0; nf < 8; ++nf) {
        int br = nf * 16 + (lane & 15);
        s16x8 bf = *(const s16x8*)&Blds[cur][br * 64 + ((ce + kk * 32) ^ ((br & 7) << 3))];
        acc[nf] = __builtin_amdgcn_mfma_f32_16x16x32_bf16(af, bf, acc[nf], 0, 0, 0);
      }
    }
    asm volatile("s_waitcnt vmcnt(0)" ::: "memory");
    __builtin_amdgcn_s_barrier();
  }
#pragma unroll
  for (int q = 0; q < 4; ++q) {
    int rloc = wid * 16 + (lane >> 4) * 4 + q;
#pragma unroll
    for (int nf = 0; nf < 8; ++nf) {
      int er = nf * 16 + (lane & 15);
      float v = acc[nf][q] * w8s[rloc * 8 + (er >> 4)];
      int dst = (er & 64) | ((er & 63) ^ ((rloc & 7) << 3));
      Cz[(size_t)(t0 + rloc) * 128 + dst] = f2bf(v);
    }
  }
}

// ---------------- 256^2 main GEMM: single-barrier overlapped phases -----------
__device__ inline void stg(int kt, int h, int t0, int o0,
                           const u16* __restrict__ xb, const u16* __restrict__ Wz,
                           const u16* __restrict__ Cz, const u16* __restrict__ Bz,
                           u16* AshP, u16* BshP, int tid) {
  if (kt >= NT_TILES) kt = NT_TILES - 1;   // tail clamp: same-value rewrite, benign
  int p = kt & 1;
  const u16* src; int ld; size_t r0; int c0; u16* dst;
  if (h < 2) {
    if (kt < 32) { src = xb; ld = D_DIM; c0 = kt * 64; }
    else         { src = Cz; ld = 128;   c0 = (kt - 32) * 64; }
    r0 = (size_t)t0 + h * 128;
    dst = AshP + p * 16384 + h * 8192;
  } else {
    if (kt < 32) { src = Wz; ld = D_DIM; c0 = kt * 64; }
    else         { src = Bz; ld = 128;   c0 = (kt - 32) * 64; }
    r0 = (size_t)o0 + (h - 2) * 128;
    dst = BshP + p * 16384 + (h - 2) * 8192;
  }
#pragma unroll
  for (int i = 0; i < 2; ++i) {
    const u16* g = src + (r0 + i * 64 + (tid >> 3)) * (size_t)ld + c0 + (tid & 7) * 8;
    __builtin_amdgcn_global_load_lds(
        (const __attribute__((address_space(1))) void*)g,
        (__attribute__((address_space(3))) void*)(dst + i * 4096 + tid * 8), 16, 0, 0);
  }
}

__device__ inline void read_af(const u16* buf, int rbase, int ce, s16x8 a[4][2]) {
#pragma unroll
  for (int i = 0; i < 4; ++i)
#pragma unroll
    for (int kk = 0; kk < 2; ++kk) {
      int r = rbase + i * 16;
      a[i][kk] = *(const s16x8*)&buf[r * 64 + ((ce + kk * 32) ^ ((r & 7) << 3))];
    }
}

__device__ inline void read_b2(const u16* buf, int rbase, int ce, s16x8 b[4][2], int h) {
#pragma unroll
  for (int i = 0; i < 2; ++i)
#pragma unroll
    for (int kk = 0; kk < 2; ++kk) {
      int r = rbase + (h * 2 + i) * 16;
      b[h * 2 + i][kk] = *(const s16x8*)&buf[r * 64 + ((ce + kk * 32) ^ ((r & 7) << 3))];
    }
}

template <int MFH, int NFH>
__device__ inline void mfma_quad(f32x4 acc[8][4], const s16x8 a[4][2],
                                 const s16x8 b[4][2]) {
#pragma unroll
  for (int i = 0; i < 4; ++i)
#pragma unroll
    for (int j = 0; j < 2; ++j)
#pragma unroll
      for (int kk = 0; kk < 2; ++kk)
        acc[MFH * 4 + i][NFH * 2 + j] = __builtin_amdgcn_mfma_f32_16x16x32_bf16(
            a[i][kk], b[NFH * 2 + j][kk], acc[MFH * 4 + i][NFH * 2 + j], 0, 0, 0);
}

__global__ __launch_bounds__(512, 2) void k_main8(const u16* __restrict__ xb,
                                                  const u16* __restrict__ Wz,
                                                  const u16* __restrict__ Cz,
                                                  const u16* __restrict__ Bz,
                                                  float* __restrict__ out) {
  __shared__ u16 Ash[2][16384];
  __shared__ u16 Bsh[2][16384];
  const int tid = threadIdx.x, lane = tid & 63;
  const int wid = tid >> 6, wm = wid >> 2, wn = wid & 3;
  int bid = blockIdx.x;                     // 512 blocks, 512 % 8 == 0
  int swz = (bid & 7) * 64 + (bid >> 3);    // XCD-aware, bijective
  int mt = swz >> 3, nt = swz & 7;
  int t0 = mt * 256, o0 = nt * 256;
  const int ce = (lane >> 4) * 8;
  const int arb = wm * 128 + (lane & 15);
  const int brb = wn * 64 + (lane & 15);
  u16* A0 = &Ash[0][0];
  u16* B0 = &Bsh[0][0];

  f32x4 acc[8][4];
#pragma unroll
  for (int m = 0; m < 8; ++m)
#pragma unroll
    for (int n = 0; n < 4; ++n) acc[m][n] = (f32x4){0.f, 0.f, 0.f, 0.f};
  s16x8 a[4][2], b[4][2];

  // prologue: T0 all halves (8 loads) + T1 A0,A1,B0 (6 loads); drain T0 only
  stg(0, 0, t0, o0, xb, Wz, Cz, Bz, A0, B0, tid);
  stg(0, 1, t0, o0, xb, Wz, Cz, Bz, A0, B0, tid);
  stg(0, 2, t0, o0, xb, Wz, Cz, Bz, A0, B0, tid);
  stg(0, 3, t0, o0, xb, Wz, Cz, Bz, A0, B0, tid);
  stg(1, 0, t0, o0, xb, Wz, Cz, Bz, A0, B0, tid);
  stg(1, 1, t0, o0, xb, Wz, Cz, Bz, A0, B0, tid);
  stg(1, 2, t0, o0, xb, Wz, Cz, Bz, A0, B0, tid);
  asm volatile("s_waitcnt vmcnt(6)" ::: "memory");
  __builtin_amdgcn_s_barrier();
  __builtin_amdgcn_sched_barrier(0);
  read_af(&Ash[0][0], arb, ce, a);          // a_lo of T0
  read_b2(&Bsh[0][0], brb, ce, b, 0);       // b_lo of T0

  for (int kt = 0; kt < NT_TILES; ++kt) {
    const int p = kt & 1;
    const u16* Abuf = &Ash[p][0];
    const u16* Bbuf = &Bsh[p][0];
    // P1: q(0,0) on pre-issued a_lo,b_lo; then issue b_hi + stage B1(kt+1)
    asm volatile("s_waitcnt lgkmcnt(0)" ::: "memory");
    __builtin_amdgcn_sched_barrier(0);
    __builtin_amdgcn_s_setprio(1);
    mfma_quad<0, 0>(acc, a, b);
    __builtin_amdgcn_s_setprio(0);
    read_b2(Bbuf, brb, ce, b, 1);
    stg(kt + 1, 3, t0, o0, xb, Wz, Cz, Bz, A0, B0, tid);
    __builtin_amdgcn_s_barrier();
    __builtin_amdgcn_sched_barrier(0);
    // P2: q(0,1) = a_lo x b_hi; then overwrite a[] with a_hi
    asm volatile("s_waitcnt lgkmcnt(0)" ::: "memory");
    __builtin_amdgcn_sched_barrier(0);
    __builtin_amdgcn_s_setprio(1);
    mfma_quad<0, 1>(acc, a, b);
    __builtin_amdgcn_s_setprio(0);
    read_af(Abuf, arb + 64, ce, a);
    __builtin_amdgcn_s_barrier();
    __builtin_amdgcn_sched_barrier(0);
    // P3: q(1,0) = a_hi x b_lo; stage A0,A1,B0(kt+2); counted vmcnt(6)
    asm volatile("s_waitcnt lgkmcnt(0)" ::: "memory");
    __builtin_amdgcn_sched_barrier(0);
    __builtin_amdgcn_s_setprio(1);
    mfma_quad<1, 0>(acc, a, b);
    __builtin_amdgcn_s_setprio(0);
    stg(kt + 2, 0, t0, o0, xb, Wz, Cz, Bz, A0, B0, tid);
    stg(kt + 2, 1, t0, o0, xb, Wz, Cz, Bz, A0, B0, tid);
    stg(kt + 2, 2, t0, o0, xb, Wz, Cz, Bz, A0, B0, tid);
    asm volatile("s_waitcnt vmcnt(6)" ::: "memory");   // drains tile kt+1 fully
    __builtin_amdgcn_s_barrier();
    __builtin_amdgcn_sched_barrier(0);
    // P4: q(1,1) = a_hi x b_hi (all in regs); pre-issue next tile a_lo,b_lo
    __builtin_amdgcn_s_setprio(1);
    mfma_quad<1, 1>(acc, a, b);
    __builtin_amdgcn_s_setprio(0);
    read_af(&Ash[p ^ 1][0], arb, ce, a);
    read_b2(&Bsh[p ^ 1][0], brb, ce, b, 0);
    __builtin_amdgcn_s_barrier();
    __builtin_amdgcn_sched_barrier(0);
  }
  asm volatile("s_waitcnt vmcnt(0) lgkmcnt(0)" ::: "memory");

#pragma unroll
  for (int mf = 0; mf < 8; ++mf)
#pragma unroll
    for (int q = 0; q < 4; ++q) {
      int row = t0 + wm * 128 + mf * 16 + (lane >> 4) * 4 + q;
#pragma unroll
      for (int nf = 0; nf < 4; ++nf) {
        int col = o0 + wn * 64 + nf * 16 + (lane & 15);
        out[(size_t)row * OUT_DIM + col] = acc[mf][nf][q];
      }
    }
}

extern "C" void kernel_launch(void* const* d_in, const int* in_sizes, int n_in,
                              void* d_out, int out_size, void* d_ws, size_t ws_size,
                              hipStream_t stream) {
  const float* x  = (const float*)d_in[0];
  const float* W  = (const float*)d_in[1];
  const float* rw = (const float*)d_in[2];
  const float* eA = (const float*)d_in[3];
  const float* eB = (const float*)d_in[4];
  float* out = (float*)d_out;
  char* ws = (char*)d_ws;
  if (ws_size < WS_BIG) return;

  u16*   Wz = (u16*)(ws + WZ_OFF);
  u16*   Az = (u16*)(ws + AZ_OFF);
  u16*   Bz = (u16*)(ws + BZ_OFF);
  u16*   Cz = (u16*)(ws + CZ_OFF);
  float* w8 = (float*)(ws + W8_OFF);
  u16*   xb = (u16*)(ws + XB_OFF);

  k_prep_router<<<10240, 256, 0, stream>>>(W, eA, eB, x, rw, Wz, Az, Bz, w8, xb);
  k_lora64<<<256, 256, 0, stream>>>(xb, Az, w8, Cz);
  k_main8<<<512, 512, 0, stream>>>(xb, Wz, Cz, Bz, out);
}